// Round 2
// 102.290 us; speedup vs baseline: 1.1090x; 1.1090x over previous
//
#include <hip/hip_runtime.h>
#include <hip/hip_bf16.h>

// B=32, D=128, H=256, O=10.
// s = 1-tanh(W1^T x + b1)^2, u = -2 z s, P = W1^T W1 (HxH).
// Rank-10 structure (M = W2 W2^T):
//   sw2[g,o] = s_g W2[g,o]; F1 = W1 sw2 (128x10); E = W1^T F1 (256x10)
//   y_o = sum_h W2[h,o] u_h w_h^2  (w = W1^T v)
//   a_un = W1 (s o (W2 y)) = F1 y          <-- identity: kills two gather loops
//   C[o,p] = sum_g sw2[g,o] E[g,p] (10x10), CW = C W2^T
//   F^2 = 2 sum u_h u_h' (P^2 o Q + P o R o R^T)  (block-diag coverage as before)
//   a_i = -a_un[i]/((F+1e-6)(||v||+1e-6))
// Out rows 0..31 = dev_velocity, rows 32..63 = a - 0.1*deviation.

#define NB 32

// workspace float offsets (unchanged layout)
#define OP    0        // 65536   P [h*256+g]
#define OE    65536    // 32*256*12: [0..9]=E, [10]=u, [11]=0
#define OCW   163840   // 32*10*256: CW[b][o][h']
#define OAUN  245760   // 32*128
#define OVN   249856   // 32

template<int BF> __device__ __forceinline__ float ld(const void* p, int i) {
  if constexpr (BF) return __bfloat162float(((const __hip_bfloat16*)p)[i]);
  else return ((const float*)p)[i];
}
template<int BF> __device__ __forceinline__ void st(void* p, int i, float v) {
  if constexpr (BF) ((__hip_bfloat16*)p)[i] = __float2bfloat16(v);
  else ((float*)p)[i] = v;
}
__device__ __forceinline__ float b2f(unsigned short u) {
  return __uint_as_float(((unsigned int)u) << 16);
}
// 4 consecutive elements, idx must be %4==0
template<int BF> __device__ __forceinline__ float4 ld4(const void* p, int i) {
  if constexpr (BF) {
    ushort4 u = *(const ushort4*)((const unsigned short*)p + i);
    return make_float4(b2f(u.x), b2f(u.y), b2f(u.z), b2f(u.w));
  } else {
    return *(const float4*)((const float*)p + i);
  }
}

// dtype sniff: view first 256 half-words of state_batch as bf16. fp32 storage
// puts random-exponent garbage in the low halves -> some |v|>1000 w.p. ~1.
__device__ __forceinline__ int blocksniff(const void* sb, int* sh) {
  if (threadIdx.x == 0) *sh = 0;
  __syncthreads();
  float v = fabsf(__bfloat162float(((const __hip_bfloat16*)sb)[threadIdx.x & 255]));
  if (!(v < 1000.0f)) atomicOr(sh, 1);
  __syncthreads();
  return (*sh == 0) ? 1 : 0;
}

// LDS carve (floats) for K1 batch path
#define LXS   0       // 128
#define LVS   128     // 128
#define LW2   256     // 2560
#define LYS   2816    // 10 (+pad)
#define LRED  2832    // 4 waves * 12
#define LF1   2880    // 128*12
#define LEL   4416    // 256*12
#define LSW2  7488    // 256*12
#define LCL   10560   // 100
#define LCL2  10660   // 100
#define LTOT  10760   // ~43 KB

#define F1ACC(wv, gidx) do { \
    const float* sp_ = &sm[LSW2 + (gidx)*12]; \
    float4 s0_ = *(const float4*)sp_; \
    float4 s1_ = *(const float4*)(sp_+4); \
    float2 s2_ = *(const float2*)(sp_+8); \
    fa[0]+=(wv)*s0_.x; fa[1]+=(wv)*s0_.y; fa[2]+=(wv)*s0_.z; fa[3]+=(wv)*s0_.w; \
    fa[4]+=(wv)*s1_.x; fa[5]+=(wv)*s1_.y; fa[6]+=(wv)*s1_.z; fa[7]+=(wv)*s1_.w; \
    fa[8]+=(wv)*s2_.x; fa[9]+=(wv)*s2_.y; \
  } while (0)

template<int BF>
__device__ void k1_body(const void* tin, const void* sbin, const void* x0in,
                        const void* x1in, const void* W1in, const void* b1in,
                        const void* W2in, float* ws, float* sm) {
  int bid = blockIdx.x, t = threadIdx.x;
  if (bid >= NB) {
    // P row (batch blocks scheduled first: they are the critical path)
    int row = bid - NB;
    float* colh = sm;            // 128
    if (t < 128) colh[t] = ld<BF>(W1in, t * 256 + row);
    __syncthreads();
    float pacc = 0.f;
    for (int d = 0; d < 128; d += 4) {
      float4 c4 = *(const float4*)&colh[d];
      pacc += c4.x * ld<BF>(W1in, (d + 0) * 256 + t);
      pacc += c4.y * ld<BF>(W1in, (d + 1) * 256 + t);
      pacc += c4.z * ld<BF>(W1in, (d + 2) * 256 + t);
      pacc += c4.w * ld<BF>(W1in, (d + 3) * 256 + t);
    }
    ws[OP + row * 256 + t] = pacc;
    return;
  }
  int b = bid;
  int w = t >> 6;
  float tt = ld<BF>(tin, 0);
  float window = 4.f * tt * (1.f - tt);
  if (t < 128) {
    float dev = ld<BF>(sbin, b * 128 + t);
    float v   = ld<BF>(sbin, (NB + b) * 128 + t);
    float x0v = ld<BF>(x0in, b * 128 + t);
    float x1v = ld<BF>(x1in, b * 128 + t);
    sm[LXS + t] = x0v + tt * (x1v - x0v) + window * dev;
    sm[LVS + t] = v;
  }
  for (int i = t; i < 2560; i += 256) sm[LW2 + i] = ld<BF>(W2in, i);
  __syncthreads();                                   // (1)
  // h, w projections (coalesced column reads)
  float hacc = ld<BF>(b1in, t), wacc = 0.f;
  for (int d = 0; d < 128; d += 4) {
    float4 xv = *(const float4*)&sm[LXS + d];
    float4 vv = *(const float4*)&sm[LVS + d];
    float w0 = ld<BF>(W1in, (d + 0) * 256 + t);
    float w1 = ld<BF>(W1in, (d + 1) * 256 + t);
    float w2 = ld<BF>(W1in, (d + 2) * 256 + t);
    float w3 = ld<BF>(W1in, (d + 3) * 256 + t);
    hacc += w0 * xv.x + w1 * xv.y + w2 * xv.z + w3 * xv.w;
    wacc += w0 * vv.x + w1 * vv.y + w2 * vv.z + w3 * vv.w;
  }
  float z  = tanhf(hacc);
  float sg = 1.f - z * z;
  float ug = -2.f * z * sg;
  // own W2 row to regs; sw2 row = s_g * W2 row
  float w2r[10];
  #pragma unroll
  for (int o = 0; o < 10; ++o) w2r[o] = sm[LW2 + t * 10 + o];
  #pragma unroll
  for (int o = 0; o < 10; ++o) sm[LSW2 + t * 12 + o] = sg * w2r[o];
  // wave-parallel reductions: y[0..9] and ||v||^2 (payload slot 10)
  float cval = ug * wacc * wacc;
  float rv[11];
  #pragma unroll
  for (int o = 0; o < 10; ++o) rv[o] = cval * w2r[o];
  rv[10] = (t < 128) ? sm[LVS + t] * sm[LVS + t] : 0.f;
  #pragma unroll
  for (int o = 0; o < 11; ++o) {
    float v = rv[o];
    #pragma unroll
    for (int m = 32; m > 0; m >>= 1) v += __shfl_xor(v, m);
    if ((t & 63) == 0) sm[LRED + w * 12 + o] = v;
  }
  __syncthreads();                                   // (2) sw2 + LRED ready
  if (t < 11) {
    float s = sm[LRED + t] + sm[LRED + 12 + t] + sm[LRED + 24 + t] + sm[LRED + 36 + t];
    if (t < 10) sm[LYS + t] = s;
    else        ws[OVN + b] = sqrtf(s);
  }
  // F1[r,o] = sum_g W1[r,g] sw2[g,o]; each thread does half the g-range of one row
  int half = t >> 7, r = t & 127;
  float fa[10];
  #pragma unroll
  for (int o = 0; o < 10; ++o) fa[o] = 0.f;
  {
    const int gbase = half * 128;
    for (int gg = 0; gg < 128; gg += 4) {
      int g = gbase + gg;
      float4 w4 = ld4<BF>(W1in, r * 256 + g);   // vectorized row gather
      F1ACC(w4.x, g + 0);
      F1ACC(w4.y, g + 1);
      F1ACC(w4.z, g + 2);
      F1ACC(w4.w, g + 3);
    }
  }
  if (half) {
    #pragma unroll
    for (int o = 0; o < 10; ++o) sm[LF1 + r * 12 + o] = fa[o];
  }
  __syncthreads();                                   // (3) upper partials in LDS
  if (!half) {   // t < 128: finalize F1 row, a_un = F1 . y
    float aun = 0.f;
    #pragma unroll
    for (int o = 0; o < 10; ++o) {
      float f = fa[o] + sm[LF1 + r * 12 + o];
      sm[LF1 + r * 12 + o] = f;
      aun += f * sm[LYS + o];
    }
    ws[OAUN + b * 128 + t] = aun;
  }
  __syncthreads();                                   // (4) F1 final
  // E[t,o] = sum_d W1[d,t] F1[d,o]  (coalesced column reads, broadcast LDS)
  float er[10];
  #pragma unroll
  for (int o = 0; o < 10; ++o) er[o] = 0.f;
  for (int d = 0; d < 128; ++d) {
    float w1v = ld<BF>(W1in, d * 256 + t);
    const float* fp = &sm[LF1 + d * 12];
    float4 a0 = *(const float4*)fp;
    float4 a1 = *(const float4*)(fp + 4);
    float2 a2 = *(const float2*)(fp + 8);
    er[0] += w1v * a0.x; er[1] += w1v * a0.y; er[2] += w1v * a0.z; er[3] += w1v * a0.w;
    er[4] += w1v * a1.x; er[5] += w1v * a1.y; er[6] += w1v * a1.z; er[7] += w1v * a1.w;
    er[8] += w1v * a2.x; er[9] += w1v * a2.y;
  }
  #pragma unroll
  for (int o = 0; o < 10; ++o) sm[LEL + t * 12 + o] = er[o];
  {
    float* gp = ws + OE + (b * 256 + t) * 12;
    *(float4*)gp       = make_float4(er[0], er[1], er[2], er[3]);
    *(float4*)(gp + 4) = make_float4(er[4], er[5], er[6], er[7]);
    *(float4*)(gp + 8) = make_float4(er[8], er[9], ug, 0.f);
  }
  __syncthreads();                                   // (5) E in LDS
  // C[o,p] = sum_g sw2[g,o] E[g,p] -- 200 threads, split g-range
  float cpart = 0.f;
  if (t < 200) {
    int gh = (t >= 100) ? 1 : 0;
    int idx = t - gh * 100;
    int o = idx / 10, p = idx - o * 10;
    const float* sa = &sm[LSW2 + gh * 1536 + o];
    const float* sb = &sm[LEL  + gh * 1536 + p];
    #pragma unroll 4
    for (int g = 0; g < 128; ++g) cpart += sa[g * 12] * sb[g * 12];
    if (gh) sm[LCL2 + idx] = cpart;
  }
  __syncthreads();                                   // (6)
  if (t < 100) sm[LCL + t] = cpart + sm[LCL2 + t];
  __syncthreads();                                   // (7)
  // CW[o,t] = sum_p C[o,p] W2[t,p]
  #pragma unroll
  for (int o = 0; o < 10; ++o) {
    float cw = 0.f;
    #pragma unroll
    for (int p = 0; p < 10; ++p) cw += sm[LCL + o * 10 + p] * w2r[p];
    ws[OCW + b * 2560 + o * 256 + t] = cw;
  }
}

__global__ __launch_bounds__(256) void K1(const void* tin, const void* sbin,
                                          const void* x0in, const void* x1in,
                                          const void* W1in, const void* b1in,
                                          const void* W2in, float* ws) {
  __shared__ int sh;
  __shared__ __align__(16) float sm[LTOT];
  int bf = blocksniff(sbin, &sh);
  if (bf) k1_body<1>(tin, sbin, x0in, x1in, W1in, b1in, W2in, ws, sm);
  else    k1_body<0>(tin, sbin, x0in, x1in, W1in, b1in, W2in, ws, sm);
}

template<int BF>
__device__ void k2_body(const void* sbin, const void* W2in, void* out, float* ws,
                        float* rec, float* w2h, float* red) {
  int b = blockIdx.x, t = threadIdx.x;
  int w = t >> 6;
  {
    float4* rec4 = (float4*)rec;
    const float4* src = (const float4*)(ws + OE + b * 3072);
    for (int i = t; i < 768; i += 256) rec4[i] = src[i];
  }
  for (int i = t; i < 3072; i += 256) {
    int r = i / 12, c = i - r * 12;
    w2h[i] = (c < 10) ? ld<BF>(W2in, r * 10 + c) : 0.f;
  }
  __syncthreads();
  float cwr[10], er[10], w2r[10];
  #pragma unroll
  for (int o = 0; o < 10; ++o) cwr[o] = ws[OCW + b * 2560 + o * 256 + t];
  float uT;
  {
    float4 e0 = *(const float4*)&rec[t * 12];
    float4 e1 = *(const float4*)&rec[t * 12 + 4];
    float4 e2 = *(const float4*)&rec[t * 12 + 8];
    er[0]=e0.x; er[1]=e0.y; er[2]=e0.z; er[3]=e0.w;
    er[4]=e1.x; er[5]=e1.y; er[6]=e1.z; er[7]=e1.w;
    er[8]=e2.x; er[9]=e2.y; uT = e2.z;
    float4 p0 = *(const float4*)&w2h[t * 12];
    float4 p1 = *(const float4*)&w2h[t * 12 + 4];
    float2 p2 = *(const float2*)&w2h[t * 12 + 8];
    w2r[0]=p0.x; w2r[1]=p0.y; w2r[2]=p0.z; w2r[3]=p0.w;
    w2r[4]=p1.x; w2r[5]=p1.y; w2r[6]=p1.z; w2r[7]=p1.w;
    w2r[8]=p2.x; w2r[9]=p2.y;
  }
  float acc = 0.f;
  for (int i0 = 0; i0 < 64; i0 += 8) {
    float ph[8];
    #pragma unroll
    for (int j = 0; j < 8; ++j)
      ph[j] = ws[OP + (w * 64 + i0 + j) * 256 + t];   // 8 loads in flight
    #pragma unroll
    for (int j = 0; j < 8; ++j) {
      int h = w * 64 + i0 + j;
      const float* rp = &rec[h * 12];
      float4 E0 = *(const float4*)rp;
      float4 E1 = *(const float4*)(rp + 4);
      float4 E2 = *(const float4*)(rp + 8);     // E8,E9,u,0
      const float* wp = &w2h[h * 12];
      float4 W0 = *(const float4*)wp;
      float4 W1v = *(const float4*)(wp + 4);
      float4 W2v = *(const float4*)(wp + 8);    // W8,W9,0,0
      float R = E0.x*w2r[0] + E0.y*w2r[1] + E0.z*w2r[2] + E0.w*w2r[3]
              + E1.x*w2r[4] + E1.y*w2r[5] + E1.z*w2r[6] + E1.w*w2r[7]
              + E2.x*w2r[8] + E2.y*w2r[9];
      float Rt = W0.x*er[0] + W0.y*er[1] + W0.z*er[2] + W0.w*er[3]
               + W1v.x*er[4] + W1v.y*er[5] + W1v.z*er[6] + W1v.w*er[7]
               + W2v.x*er[8] + W2v.y*er[9];
      float Qd = W0.x*cwr[0] + W0.y*cwr[1] + W0.z*cwr[2] + W0.w*cwr[3]
               + W1v.x*cwr[4] + W1v.y*cwr[5] + W1v.z*cwr[6] + W1v.w*cwr[7]
               + W2v.x*cwr[8] + W2v.y*cwr[9];
      acc += E2.z * ph[j] * (ph[j] * Qd + R * Rt);
    }
  }
  acc *= uT;
  #pragma unroll
  for (int m = 32; m > 0; m >>= 1) acc += __shfl_xor(acc, m);
  if ((t & 63) == 0) red[w] = acc;
  __syncthreads();
  float F = sqrtf(fmaxf(2.f * (red[0] + red[1] + red[2] + red[3]), 0.f));
  float denom = (F + 1e-6f) * (ws[OVN + b] + 1e-6f);
  if (t < 128) {
    st<BF>(out, b * 128 + t, ld<BF>(sbin, (NB + b) * 128 + t));   // dev_velocity
    float dev = ld<BF>(sbin, b * 128 + t);
    float val = -ws[OAUN + b * 128 + t] / denom - 0.1f * dev;
    st<BF>(out, (NB + b) * 128 + t, val);
  }
}

__global__ __launch_bounds__(256) void K2(const void* sbin, const void* W2in,
                                          void* out, float* ws) {
  __shared__ int sh;
  __shared__ __align__(16) float rec[3072];
  __shared__ __align__(16) float w2h[3072];
  __shared__ float red[4];
  int bf = blocksniff(sbin, &sh);
  if (bf) k2_body<1>(sbin, W2in, out, ws, rec, w2h, red);
  else    k2_body<0>(sbin, W2in, out, ws, rec, w2h, red);
}

extern "C" void kernel_launch(void* const* d_in, const int* in_sizes, int n_in,
                              void* d_out, int out_size, void* d_ws, size_t ws_size,
                              hipStream_t stream) {
  float* ws = (float*)d_ws;
  const void* tin  = d_in[0];
  const void* sbin = d_in[1];
  const void* x0in = d_in[2];
  const void* x1in = d_in[3];
  const void* W1in = d_in[4];
  const void* b1in = d_in[5];
  const void* W2in = d_in[6];
  // d_in[7] (b2) cancels in every derivative.

  K1<<<dim3(288), dim3(256), 0, stream>>>(tin, sbin, x0in, x1in, W1in, b1in, W2in, ws);
  K2<<<dim3(32),  dim3(256), 0, stream>>>(sbin, W2in, d_out, ws);
}